// Round 4
// baseline (430.413 us; speedup 1.0000x reference)
//
#include <hip/hip_runtime.h>
#include <hip/hip_bf16.h>

#define NN 50000
#define NE 800000
#define DIN 128
#define DEIN 32
#define PD 192          // P row: [0:64) f_ni, [64:128) f_nj, [128:192) h_src(node proj)
#define NEG_SLOPE 0.2f

typedef __bf16 bf16x8 __attribute__((ext_vector_type(8)));
typedef float f32x4 __attribute__((ext_vector_type(4)));
using bf16 = __hip_bfloat16;

__device__ inline bf16x8 load8_f32_to_bf16(const float* p) {
    f32x4 a = *reinterpret_cast<const f32x4*>(p);
    f32x4 b = *reinterpret_cast<const f32x4*>(p + 4);
    bf16x8 r;
#pragma unroll
    for (int j = 0; j < 4; j++) {
        r[j]     = (__bf16)a[j];
        r[j + 4] = (__bf16)b[j];
    }
    return r;
}

__device__ inline void async_copy16(const void* g, void* lds) {
    __builtin_amdgcn_global_load_lds(
        (const __attribute__((address_space(1))) void*)g,
        (__attribute__((address_space(3))) void*)lds, 16, 0, 0);
}

// ---------------- K1: P = nfeats @ [W_ni | W_nj | W_node], LDS-staged W ----------------
__global__ __launch_bounds__(256) void k_node_gemm(
    const float* __restrict__ nfeats,
    const float* __restrict__ Wni, const float* __restrict__ Wnj,
    const float* __restrict__ Wnode,
    bf16* __restrict__ P)
{
    __shared__ __align__(16) __bf16 sW[16][136];   // [col][k], pad->2-way-free
    const int lane = threadIdx.x & 63;
    const int wid  = threadIdx.x >> 6;
    const int lo = lane & 15, hi = lane >> 4;
    const int rbase = blockIdx.x * 64 + wid * 16;

    bf16x8 afrag[4];
#pragma unroll
    for (int kk = 0; kk < 4; kk++) {
        int row = rbase + lo; if (row >= NN) row = NN - 1;
        afrag[kk] = load8_f32_to_bf16(&nfeats[(size_t)row*DIN + kk*32 + hi*8]);
    }

    for (int ct = 0; ct < 12; ct++) {
        const float* W; int cw;
        if (ct < 4)      { W = Wni;   cw = ct*16; }
        else if (ct < 8) { W = Wnj;   cw = (ct-8+4)*16; }
        else             { W = Wnode; cw = (ct-8)*16; }
        __syncthreads();
#pragma unroll
        for (int q = 0; q < 8; q++) {
            int idx = threadIdx.x * 8 + q;      // 2048 = 16 cols x 128 k
            int col = idx >> 7, k = idx & 127;
            sW[col][k] = (__bf16)W[k*64 + cw + col];
        }
        __syncthreads();
        f32x4 acc = {0.f, 0.f, 0.f, 0.f};
#pragma unroll
        for (int kk = 0; kk < 4; kk++) {
            bf16x8 bfrag = *reinterpret_cast<const bf16x8*>(&sW[lo][kk*32 + hi*8]);
            acc = __builtin_amdgcn_mfma_f32_16x16x32_bf16(afrag[kk], bfrag, acc, 0, 0, 0);
        }
#pragma unroll
        for (int r = 0; r < 4; r++) {
            int row = rbase + hi*4 + r;
            if (row < NN) P[(size_t)row*PD + ct*16 + lo] = __float2bfloat16(acc[r]);
        }
    }
}

// ---------------- CSR build ----------------
__global__ void k_zero(int* __restrict__ counts, int n) {
    int i = blockIdx.x * blockDim.x + threadIdx.x;
    if (i < n) counts[i] = 0;
}

__global__ void k_hist(const int* __restrict__ dst, int* __restrict__ counts, int e) {
    int i = blockIdx.x * blockDim.x + threadIdx.x;
    if (i < e) atomicAdd(&counts[dst[i]], 1);
}

// single-block exclusive scan; writes offsets AND cursor (scatter mutates cursor)
__global__ __launch_bounds__(1024) void k_scan(const int* __restrict__ counts,
                                               int* __restrict__ offsets,
                                               int* __restrict__ cursor, int n) {
    __shared__ int wsum[16];
    __shared__ int chunk_carry;
    if (threadIdx.x == 0) chunk_carry = 0;
    __syncthreads();
    const int lane = threadIdx.x & 63;
    const int wid  = threadIdx.x >> 6;
    for (int base = 0; base < n; base += 8192) {
        const int i0 = base + threadIdx.x * 8;
        int v[8], tsum = 0;
#pragma unroll
        for (int j = 0; j < 8; j++) {
            int idx = i0 + j;
            v[j] = (idx < n) ? counts[idx] : 0;
            tsum += v[j];
        }
        int sc = tsum;
#pragma unroll
        for (int s = 1; s < 64; s <<= 1) {
            int t = __shfl_up(sc, s);
            if (lane >= s) sc += t;
        }
        if (lane == 63) wsum[wid] = sc;
        __syncthreads();
        int woff = 0;
        for (int k = 0; k < wid; k++) woff += wsum[k];
        int run = chunk_carry + woff + (sc - tsum);
#pragma unroll
        for (int j = 0; j < 8; j++) {
            int idx = i0 + j;
            if (idx < n) { offsets[idx] = run; cursor[idx] = run; }
            run += v[j];
        }
        __syncthreads();
        if (threadIdx.x == 1023) chunk_carry += woff + sc;
        __syncthreads();
    }
    if (threadIdx.x == 0) offsets[n] = chunk_carry;
}

__global__ void k_scatter(const int* __restrict__ dst,
                          int* __restrict__ cursor, int* __restrict__ eidx, int e) {
    int i = blockIdx.x * blockDim.x + threadIdx.x;
    if (i < e) {
        int p = atomicAdd(&cursor[dst[i]], 1);
        eidx[p] = i;
    }
}

// ---------------- K2: fused edge stage ----------------
// block = 64 edges / 4 waves. P_i/P_j gathered async into LDS (full-row 128B txns),
// f_out written via LDS transpose as contiguous 1KB wave stores.
__global__ __launch_bounds__(256) void k_edge(
    const float* __restrict__ efeats,
    const float* __restrict__ Wf,     // [32][64] f32
    const float* __restrict__ attn,   // [64] f32
    const float* __restrict__ bias,   // [64] f32
    const bf16* __restrict__ P,       // [NN][192] bf16
    const int* __restrict__ src, const int* __restrict__ dst,
    float* __restrict__ f_out,        // [NE][64] f32
    float* __restrict__ el)           // [NE][4]
{
    __shared__ __align__(16) __bf16 sP[2][64][64];   // 16KB, linear (global_load_lds dest)
    __shared__ int sIdx[2][64];
    const int t = threadIdx.x;
    const int lane = t & 63, wid = t >> 6;
    const int lo = lane & 15, hi = lane >> 4;
    const int e0 = blockIdx.x * 64;

    if (t < 64) sIdx[0][t] = src[e0 + t];
    else if (t < 128) sIdx[1][t - 64] = dst[e0 + t - 64];
    __syncthreads();

    // 1024 chunks of 16B (2 tables x 64 rows x 8 parts), 4 per thread.
#pragma unroll
    for (int q = 0; q < 4; q++) {
        int c = t + q * 256;
        int table = c >> 9, row = (c >> 3) & 63, part = c & 7;
        const bf16* g = P + (size_t)sIdx[table][row] * PD + table * 64 + part * 8;
        __bf16* ldsbase = &sP[0][0][0] + (size_t)(c & ~63) * 8;   // wave-uniform
        async_copy16(g, ldsbase);
    }

    bf16x8 afrag = load8_f32_to_bf16(&efeats[(size_t)(e0 + wid*16 + lo)*DEIN + hi*8]);
    bf16x8 bfr[4];
#pragma unroll
    for (int ct = 0; ct < 4; ct++)
#pragma unroll
        for (int j = 0; j < 8; j++)
            bfr[ct][j] = (__bf16)Wf[(hi*8 + j)*64 + ct*16 + lo];

    __syncthreads();   // drains vmcnt (gathers in LDS) + barrier

    float v[4][4];     // [ct][r]
#pragma unroll
    for (int ct = 0; ct < 4; ct++) {
        f32x4 acc = {0.f, 0.f, 0.f, 0.f};
        acc = __builtin_amdgcn_mfma_f32_16x16x32_bf16(afrag, bfr[ct], acc, 0, 0, 0);
        const int c = ct*16 + lo;
        const float att = attn[c];
        const float bs  = bias[c];
#pragma unroll
        for (int r = 0; r < 4; r++) {
            const int lrow = wid*16 + hi*4 + r;
            float x = acc[r]
                    + __bfloat162float(sP[0][lrow][c])
                    + __bfloat162float(sP[1][lrow][c])
                    + bs;
            x = x > 0.f ? x : NEG_SLOPE * x;
            v[ct][r] = x;
            float s = x * att;
            s += __shfl_xor(s, 1);
            s += __shfl_xor(s, 2);
            s += __shfl_xor(s, 4);
            s += __shfl_xor(s, 8);
            if (lo == 0) el[(size_t)(e0 + lrow)*4 + ct] = s;
        }
    }

    __syncthreads();   // all waves done reading sP -> reuse as f32 transpose buffer
    float* sOut = reinterpret_cast<float*>(&sP[0][0][0]) + wid * 1024;  // 16x64 f32
#pragma unroll
    for (int ct = 0; ct < 4; ct++)
#pragma unroll
        for (int r = 0; r < 4; r++)
            sOut[(hi*4 + r)*64 + ct*16 + lo] = v[ct][r];
#pragma unroll
    for (int q = 0; q < 4; q++) {
        const int lrow = (lane >> 4) + q*4;
        const int c4   = (lane & 15) * 4;
        f32x4 o = *reinterpret_cast<const f32x4*>(&sOut[lrow*64 + c4]);
        *reinterpret_cast<f32x4*>(&f_out[(size_t)(e0 + wid*16 + lrow)*64 + c4]) = o;
    }
}

// ---------------- K4: per-dst-node online softmax + weighted aggregation ----------------
__global__ __launch_bounds__(256) void k_aggregate(
    const int* __restrict__ offsets, const int* __restrict__ eidx,
    const int* __restrict__ src, const float* __restrict__ el,
    const bf16* __restrict__ P, float* __restrict__ h_out)
{
    const int lane = threadIdx.x & 63;
    const int wid  = threadIdx.x >> 6;
    const int n = blockIdx.x * 4 + wid;
    if (n >= NN) return;
    const int h = lane >> 4;
    const int off0 = offsets[n], off1 = offsets[n + 1];
    float m = -3.0e38f, den = 0.f, acc = 0.f;
    for (int t = off0; t < off1; t++) {
        const int e = eidx[t];
        const int s = src[e];
        const float lv = el[(size_t)e*4 + h];
        const float p  = __bfloat162float(P[(size_t)s*PD + 128 + lane]);
        const float nm = fmaxf(m, lv);
        const float scale = __expf(m - nm);
        const float w = __expf(lv - nm);
        den = den * scale + w;
        acc = acc * scale + w * p;
        m = nm;
    }
    const float o = (off1 > off0) ? acc / den : 0.f;
    h_out[(size_t)n*64 + lane] = o;
}

extern "C" void kernel_launch(void* const* d_in, const int* in_sizes, int n_in,
                              void* d_out, int out_size, void* d_ws, size_t ws_size,
                              hipStream_t stream) {
    const float* nfeats = (const float*)d_in[0];
    const float* efeats = (const float*)d_in[1];
    const float* Wni    = (const float*)d_in[2];
    const float* Wnj    = (const float*)d_in[3];
    const float* Wfij   = (const float*)d_in[4];
    const float* Wnode  = (const float*)d_in[5];
    const float* attn   = (const float*)d_in[6];
    const float* bias   = (const float*)d_in[7];
    const int*   src    = (const int*)d_in[8];
    const int*   dst    = (const int*)d_in[9];

    float* h_out = (float*)d_out;                           // [NN*64]
    float* f_out = (float*)d_out + (size_t)NN * 64;         // [NE*64]

    char* ws = (char*)d_ws;
    size_t off = 0;
    auto carve = [&](size_t bytes) -> void* {
        void* p = ws + off;
        off = (off + bytes + 255) & ~(size_t)255;
        return p;
    };
    bf16*  P       = (bf16*) carve((size_t)NN * PD * sizeof(bf16));
    float* el      = (float*)carve((size_t)NE * 4 * sizeof(float));
    int*   counts  = (int*)  carve((size_t)NN * sizeof(int));
    int*   cursor  = (int*)  carve((size_t)NN * sizeof(int));
    int*   offsets = (int*)  carve((size_t)(NN + 1) * sizeof(int));
    int*   eidx    = (int*)  carve((size_t)NE * sizeof(int));
    (void)ws_size; (void)in_sizes; (void)n_in; (void)out_size;

    hipLaunchKernelGGL(k_zero, dim3((NN + 255) / 256), dim3(256), 0, stream,
                       counts, NN);
    hipLaunchKernelGGL(k_node_gemm, dim3((NN + 63) / 64), dim3(256), 0, stream,
                       nfeats, Wni, Wnj, Wnode, P);
    hipLaunchKernelGGL(k_hist, dim3((NE + 255) / 256), dim3(256), 0, stream,
                       dst, counts, NE);
    hipLaunchKernelGGL(k_scan, dim3(1), dim3(1024), 0, stream,
                       counts, offsets, cursor, NN);
    hipLaunchKernelGGL(k_scatter, dim3((NE + 255) / 256), dim3(256), 0, stream,
                       dst, cursor, eidx, NE);
    hipLaunchKernelGGL(k_edge, dim3(NE / 64), dim3(256), 0, stream,
                       efeats, Wfij, attn, bias, P, src, dst, f_out, el);
    hipLaunchKernelGGL(k_aggregate, dim3((NN + 3) / 4), dim3(256), 0, stream,
                       offsets, eidx, src, el, P, h_out);
}

// Round 5
// 334.713 us; speedup vs baseline: 1.2859x; 1.2859x over previous
//
#include <hip/hip_runtime.h>
#include <hip/hip_bf16.h>

#define NN 50000
#define NE 800000
#define DIN 128
#define DEIN 32
#define PD 192          // P row: [0:64) f_ni, [64:128) f_nj, [128:192) h_src(node proj)
#define NEG_SLOPE 0.2f

typedef __bf16 bf16x8 __attribute__((ext_vector_type(8)));
typedef float f32x4 __attribute__((ext_vector_type(4)));
using bf16 = __hip_bfloat16;

__device__ inline bf16x8 load8_f32_to_bf16(const float* p) {
    f32x4 a = *reinterpret_cast<const f32x4*>(p);
    f32x4 b = *reinterpret_cast<const f32x4*>(p + 4);
    bf16x8 r;
#pragma unroll
    for (int j = 0; j < 4; j++) {
        r[j]     = (__bf16)a[j];
        r[j + 4] = (__bf16)b[j];
    }
    return r;
}

__device__ inline void async_copy16(const void* g, void* lds) {
    __builtin_amdgcn_global_load_lds(
        (const __attribute__((address_space(1))) void*)g,
        (__attribute__((address_space(3))) void*)lds, 16, 0, 0);
}

// ---------------- K1: P = nfeats @ [W_ni | W_nj | W_node], LDS-staged W ----------------
__global__ __launch_bounds__(256) void k_node_gemm(
    const float* __restrict__ nfeats,
    const float* __restrict__ Wni, const float* __restrict__ Wnj,
    const float* __restrict__ Wnode,
    bf16* __restrict__ P)
{
    __shared__ __align__(16) __bf16 sW[16][136];   // [col][k], pad->2-way-free
    const int lane = threadIdx.x & 63;
    const int wid  = threadIdx.x >> 6;
    const int lo = lane & 15, hi = lane >> 4;
    const int rbase = blockIdx.x * 64 + wid * 16;

    bf16x8 afrag[4];
#pragma unroll
    for (int kk = 0; kk < 4; kk++) {
        int row = rbase + lo; if (row >= NN) row = NN - 1;
        afrag[kk] = load8_f32_to_bf16(&nfeats[(size_t)row*DIN + kk*32 + hi*8]);
    }

    for (int ct = 0; ct < 12; ct++) {
        const float* W; int cw;
        if (ct < 4)      { W = Wni;   cw = ct*16; }
        else if (ct < 8) { W = Wnj;   cw = (ct-8+4)*16; }
        else             { W = Wnode; cw = (ct-8)*16; }
        __syncthreads();
#pragma unroll
        for (int q = 0; q < 8; q++) {
            int idx = threadIdx.x * 8 + q;      // 2048 = 16 cols x 128 k
            int col = idx >> 7, k = idx & 127;
            sW[col][k] = (__bf16)W[k*64 + cw + col];
        }
        __syncthreads();
        f32x4 acc = {0.f, 0.f, 0.f, 0.f};
#pragma unroll
        for (int kk = 0; kk < 4; kk++) {
            bf16x8 bfrag = *reinterpret_cast<const bf16x8*>(&sW[lo][kk*32 + hi*8]);
            acc = __builtin_amdgcn_mfma_f32_16x16x32_bf16(afrag[kk], bfrag, acc, 0, 0, 0);
        }
#pragma unroll
        for (int r = 0; r < 4; r++) {
            int row = rbase + hi*4 + r;
            if (row < NN) P[(size_t)row*PD + ct*16 + lo] = __float2bfloat16(acc[r]);
        }
    }
}

// ---------------- CSR build ----------------
__global__ void k_zero(int* __restrict__ counts, int n) {
    int i = blockIdx.x * blockDim.x + threadIdx.x;
    if (i < n) counts[i] = 0;
}

__global__ void k_hist(const int* __restrict__ dst, int* __restrict__ counts, int e) {
    int i = blockIdx.x * blockDim.x + threadIdx.x;
    if (i < e) atomicAdd(&counts[dst[i]], 1);
}

// multi-block scan: per-block sums -> tiny scan of block sums -> apply
__global__ __launch_bounds__(256) void k_bsum(const int* __restrict__ counts,
                                              int* __restrict__ bsum, int n) {
    __shared__ int ws[4];
    const int gid = blockIdx.x * 256 + threadIdx.x;
    const int lane = threadIdx.x & 63, wid = threadIdx.x >> 6;
    int v = (gid < n) ? counts[gid] : 0;
#pragma unroll
    for (int s = 1; s < 64; s <<= 1) v += __shfl_xor(v, s);
    if (lane == 0) ws[wid] = v;
    __syncthreads();
    if (threadIdx.x == 0) bsum[blockIdx.x] = ws[0] + ws[1] + ws[2] + ws[3];
}

__global__ __launch_bounds__(256) void k_bscan(const int* __restrict__ bsum,
                                               int* __restrict__ bpre,
                                               int* __restrict__ offsets, int nb) {
    __shared__ int ws[4];
    const int t = threadIdx.x, lane = t & 63, wid = t >> 6;
    int v = (t < nb) ? bsum[t] : 0;
    int sc = v;
#pragma unroll
    for (int s = 1; s < 64; s <<= 1) { int u = __shfl_up(sc, s); if (lane >= s) sc += u; }
    if (lane == 63) ws[wid] = sc;
    __syncthreads();
    int woff = 0;
    for (int k = 0; k < wid; k++) woff += ws[k];
    if (t < nb) bpre[t] = woff + sc - v;
    if (t == 0) offsets[NN] = NE;
}

__global__ __launch_bounds__(256) void k_apply(const int* __restrict__ counts,
                                               const int* __restrict__ bpre,
                                               int* __restrict__ offsets,
                                               int* __restrict__ cursor, int n) {
    __shared__ int ws[4];
    const int gid = blockIdx.x * 256 + threadIdx.x;
    const int t = threadIdx.x, lane = t & 63, wid = t >> 6;
    int v = (gid < n) ? counts[gid] : 0;
    int sc = v;
#pragma unroll
    for (int s = 1; s < 64; s <<= 1) { int u = __shfl_up(sc, s); if (lane >= s) sc += u; }
    if (lane == 63) ws[wid] = sc;
    __syncthreads();
    int woff = 0;
    for (int k = 0; k < wid; k++) woff += ws[k];
    const int ex = bpre[blockIdx.x] + woff + sc - v;
    if (gid < n) { offsets[gid] = ex; cursor[gid] = ex; }
}

__global__ void k_scatter(const int* __restrict__ dst,
                          int* __restrict__ cursor, int* __restrict__ eidx, int e) {
    int i = blockIdx.x * blockDim.x + threadIdx.x;
    if (i < e) {
        int p = atomicAdd(&cursor[dst[i]], 1);
        eidx[p] = i;
    }
}

// ---------------- K2: fused edge stage ----------------
__global__ __launch_bounds__(256) void k_edge(
    const float* __restrict__ efeats,
    const float* __restrict__ Wf,     // [32][64] f32
    const float* __restrict__ attn,   // [64] f32
    const float* __restrict__ bias,   // [64] f32
    const bf16* __restrict__ P,       // [NN][192] bf16
    const int* __restrict__ src, const int* __restrict__ dst,
    float* __restrict__ f_out,        // [NE][64] f32
    float* __restrict__ el)           // [NE][4]
{
    __shared__ __align__(16) __bf16 sP[2][64][64];   // 16KB, linear (global_load_lds dest)
    __shared__ int sIdx[2][64];
    const int t = threadIdx.x;
    const int lane = t & 63, wid = t >> 6;
    const int lo = lane & 15, hi = lane >> 4;
    const int e0 = blockIdx.x * 64;

    if (t < 64) sIdx[0][t] = src[e0 + t];
    else if (t < 128) sIdx[1][t - 64] = dst[e0 + t - 64];
    __syncthreads();

    // 1024 chunks of 16B (2 tables x 64 rows x 8 parts), 4 per thread.
#pragma unroll
    for (int q = 0; q < 4; q++) {
        int c = t + q * 256;
        int table = c >> 9, row = (c >> 3) & 63, part = c & 7;
        const bf16* g = P + (size_t)sIdx[table][row] * PD + table * 64 + part * 8;
        __bf16* ldsbase = &sP[0][0][0] + (size_t)(c & ~63) * 8;   // wave-uniform
        async_copy16(g, ldsbase);
    }

    bf16x8 afrag = load8_f32_to_bf16(&efeats[(size_t)(e0 + wid*16 + lo)*DEIN + hi*8]);
    bf16x8 bfr[4];
#pragma unroll
    for (int ct = 0; ct < 4; ct++)
#pragma unroll
        for (int j = 0; j < 8; j++)
            bfr[ct][j] = (__bf16)Wf[(hi*8 + j)*64 + ct*16 + lo];

    __syncthreads();   // drains vmcnt (gathers in LDS) + barrier

    float v[4][4];     // [ct][r]
#pragma unroll
    for (int ct = 0; ct < 4; ct++) {
        f32x4 acc = {0.f, 0.f, 0.f, 0.f};
        acc = __builtin_amdgcn_mfma_f32_16x16x32_bf16(afrag, bfr[ct], acc, 0, 0, 0);
        const int c = ct*16 + lo;
        const float att = attn[c];
        const float bs  = bias[c];
#pragma unroll
        for (int r = 0; r < 4; r++) {
            const int lrow = wid*16 + hi*4 + r;
            float x = acc[r]
                    + __bfloat162float(sP[0][lrow][c])
                    + __bfloat162float(sP[1][lrow][c])
                    + bs;
            x = x > 0.f ? x : NEG_SLOPE * x;
            v[ct][r] = x;
            float s = x * att;
            s += __shfl_xor(s, 1);
            s += __shfl_xor(s, 2);
            s += __shfl_xor(s, 4);
            s += __shfl_xor(s, 8);
            if (lo == 0) el[(size_t)(e0 + lrow)*4 + ct] = s;
        }
    }

    __syncthreads();   // reuse sP as f32 transpose buffer
    float* sOut = reinterpret_cast<float*>(&sP[0][0][0]) + wid * 1024;  // 16x64 f32
#pragma unroll
    for (int ct = 0; ct < 4; ct++)
#pragma unroll
        for (int r = 0; r < 4; r++)
            sOut[(hi*4 + r)*64 + ct*16 + lo] = v[ct][r];
#pragma unroll
    for (int q = 0; q < 4; q++) {
        const int lrow = (lane >> 4) + q*4;
        const int c4   = (lane & 15) * 4;
        f32x4 o = *reinterpret_cast<const f32x4*>(&sOut[lrow*64 + c4]);
        *reinterpret_cast<f32x4*>(&f_out[(size_t)(e0 + wid*16 + lrow)*64 + c4]) = o;
    }
}

// ---------------- K4: wave-per-node, 16-edge chunked online softmax + aggregation -------
// phase1: lane=(head h=lane>>4, slot=lane&15) loads 16 edges' logits at once.
// phase2: lane=feat; 16 independent P-row gathers unrolled (MLP=16) + FMA.
__global__ __launch_bounds__(256) void k_aggregate(
    const int* __restrict__ offsets, const int* __restrict__ eidx,
    const int* __restrict__ src, const float* __restrict__ el,
    const bf16* __restrict__ P, float* __restrict__ h_out)
{
    const int lane = threadIdx.x & 63;
    const int wid  = threadIdx.x >> 6;
    const int n = blockIdx.x * 4 + wid;
    if (n >= NN) return;
    const int slot = lane & 15;
    const int grpBase = lane & 48;       // h*16
    const int h = lane >> 4;
    const int off0 = offsets[n], off1 = offsets[n + 1];

    float m = -3.0e38f, den = 0.f, acc = 0.f;
    for (int c0 = off0; c0 < off1; c0 += 16) {
        const int cnt = min(16, off1 - c0);
        float lv = -3.0e38f; int s = 0;
        if (slot < cnt) {
            const int e = eidx[c0 + slot];
            lv = el[(size_t)e*4 + h];
            s = src[e];
        }
        float cm = lv;
        cm = fmaxf(cm, __shfl_xor(cm, 1));
        cm = fmaxf(cm, __shfl_xor(cm, 2));
        cm = fmaxf(cm, __shfl_xor(cm, 4));
        cm = fmaxf(cm, __shfl_xor(cm, 8));
        const float nm = fmaxf(m, cm);
        const float scale = __expf(m - nm);
        const float w = (slot < cnt) ? __expf(lv - nm) : 0.f;
        float ws = w;
        ws += __shfl_xor(ws, 1);
        ws += __shfl_xor(ws, 2);
        ws += __shfl_xor(ws, 4);
        ws += __shfl_xor(ws, 8);
        den = den * scale + ws;
        acc *= scale;
        m = nm;

        float pv[16], wv[16];
#pragma unroll
        for (int q = 0; q < 16; q++) {
            const int sq = __shfl(s, grpBase + q);
            wv[q] = __shfl(w, grpBase + q);
            pv[q] = (q < cnt) ? __bfloat162float(P[(size_t)sq*PD + 128 + lane]) : 0.f;
        }
#pragma unroll
        for (int q = 0; q < 16; q++) acc += wv[q] * pv[q];
    }
    h_out[(size_t)n*64 + lane] = (off1 > off0) ? acc / den : 0.f;
}

extern "C" void kernel_launch(void* const* d_in, const int* in_sizes, int n_in,
                              void* d_out, int out_size, void* d_ws, size_t ws_size,
                              hipStream_t stream) {
    const float* nfeats = (const float*)d_in[0];
    const float* efeats = (const float*)d_in[1];
    const float* Wni    = (const float*)d_in[2];
    const float* Wnj    = (const float*)d_in[3];
    const float* Wfij   = (const float*)d_in[4];
    const float* Wnode  = (const float*)d_in[5];
    const float* attn   = (const float*)d_in[6];
    const float* bias   = (const float*)d_in[7];
    const int*   src    = (const int*)d_in[8];
    const int*   dst    = (const int*)d_in[9];

    float* h_out = (float*)d_out;                           // [NN*64]
    float* f_out = (float*)d_out + (size_t)NN * 64;         // [NE*64]

    char* ws = (char*)d_ws;
    size_t off = 0;
    auto carve = [&](size_t bytes) -> void* {
        void* p = ws + off;
        off = (off + bytes + 255) & ~(size_t)255;
        return p;
    };
    const int NB = (NN + 255) / 256;    // 196 scan blocks
    bf16*  P       = (bf16*) carve((size_t)NN * PD * sizeof(bf16));
    float* el      = (float*)carve((size_t)NE * 4 * sizeof(float));
    int*   counts  = (int*)  carve((size_t)NN * sizeof(int));
    int*   cursor  = (int*)  carve((size_t)NN * sizeof(int));
    int*   offsets = (int*)  carve((size_t)(NN + 1) * sizeof(int));
    int*   eidx    = (int*)  carve((size_t)NE * sizeof(int));
    int*   bsum    = (int*)  carve((size_t)NB * sizeof(int));
    int*   bpre    = (int*)  carve((size_t)NB * sizeof(int));
    (void)ws_size; (void)in_sizes; (void)n_in; (void)out_size;

    hipLaunchKernelGGL(k_zero, dim3(NB), dim3(256), 0, stream, counts, NN);
    hipLaunchKernelGGL(k_node_gemm, dim3((NN + 63) / 64), dim3(256), 0, stream,
                       nfeats, Wni, Wnj, Wnode, P);
    hipLaunchKernelGGL(k_hist, dim3((NE + 255) / 256), dim3(256), 0, stream,
                       dst, counts, NE);
    hipLaunchKernelGGL(k_bsum, dim3(NB), dim3(256), 0, stream, counts, bsum, NN);
    hipLaunchKernelGGL(k_bscan, dim3(1), dim3(256), 0, stream, bsum, bpre, offsets, NB);
    hipLaunchKernelGGL(k_apply, dim3(NB), dim3(256), 0, stream,
                       counts, bpre, offsets, cursor, NN);
    hipLaunchKernelGGL(k_scatter, dim3((NE + 255) / 256), dim3(256), 0, stream,
                       dst, cursor, eidx, NE);
    hipLaunchKernelGGL(k_edge, dim3(NE / 64), dim3(256), 0, stream,
                       efeats, Wfij, attn, bias, P, src, dst, f_out, el);
    hipLaunchKernelGGL(k_aggregate, dim3((NN + 3) / 4), dim3(256), 0, stream,
                       offsets, eidx, src, el, P, h_out);
}

// Round 6
// 300.428 us; speedup vs baseline: 1.4327x; 1.1141x over previous
//
#include <hip/hip_runtime.h>
#include <hip/hip_bf16.h>

#define NN 50000
#define NE 800000
#define DIN 128
#define DEIN 32
#define PD 192          // P row: [0:64) f_ni, [64:128) f_nj, [128:192) h_src(node proj)
#define NEG_SLOPE 0.2f

typedef __bf16 bf16x8 __attribute__((ext_vector_type(8)));
typedef float f32x4 __attribute__((ext_vector_type(4)));
using bf16 = __hip_bfloat16;

__device__ inline bf16x8 load8_f32_to_bf16(const float* p) {
    f32x4 a = *reinterpret_cast<const f32x4*>(p);
    f32x4 b = *reinterpret_cast<const f32x4*>(p + 4);
    bf16x8 r;
#pragma unroll
    for (int j = 0; j < 4; j++) {
        r[j]     = (__bf16)a[j];
        r[j + 4] = (__bf16)b[j];
    }
    return r;
}

__device__ inline void async_copy16(const void* g, void* lds) {
    __builtin_amdgcn_global_load_lds(
        (const __attribute__((address_space(1))) void*)g,
        (__attribute__((address_space(3))) void*)lds, 16, 0, 0);
}

// ---------------- K1: P = nfeats @ [W_ni | W_nj | W_node] ----------------
// 512 threads / 8 waves / 128 rows per block. All three W staged ONCE into
// transposed LDS [192 col][136 k] so each B-fragment is one ds_read_b128.
__global__ __launch_bounds__(512) void k_node_gemm(
    const float* __restrict__ nfeats,
    const float* __restrict__ Wni, const float* __restrict__ Wnj,
    const float* __restrict__ Wnode,
    bf16* __restrict__ P)
{
    __shared__ __align__(16) __bf16 sW[192][136];   // 52.2KB, [col][k], 272B rows
    const int t = threadIdx.x;
    const int lane = t & 63;
    const int wid  = t >> 6;
    const int lo = lane & 15, hi = lane >> 4;

    const float* tabs[3] = {Wni, Wnj, Wnode};
#pragma unroll
    for (int tb = 0; tb < 3; tb++) {
#pragma unroll
        for (int q = 0; q < 4; q++) {
            int flat = t + q * 512;             // 2048 f32x4 per table
            int k  = flat >> 4;
            int c4 = (flat & 15) * 4;
            f32x4 w4 = *reinterpret_cast<const f32x4*>(&tabs[tb][k * 64 + c4]);
#pragma unroll
            for (int i = 0; i < 4; i++)
                sW[tb * 64 + c4 + i][k] = (__bf16)w4[i];
        }
    }

    const int rbase = blockIdx.x * 128 + wid * 16;
    bf16x8 afrag[4];
#pragma unroll
    for (int kk = 0; kk < 4; kk++) {
        int row = rbase + lo; if (row >= NN) row = NN - 1;
        afrag[kk] = load8_f32_to_bf16(&nfeats[(size_t)row*DIN + kk*32 + hi*8]);
    }
    __syncthreads();

#pragma unroll
    for (int ct = 0; ct < 12; ct++) {
        f32x4 acc = {0.f, 0.f, 0.f, 0.f};
#pragma unroll
        for (int kk = 0; kk < 4; kk++) {
            bf16x8 bfrag = *reinterpret_cast<const bf16x8*>(&sW[ct*16 + lo][kk*32 + hi*8]);
            acc = __builtin_amdgcn_mfma_f32_16x16x32_bf16(afrag[kk], bfrag, acc, 0, 0, 0);
        }
#pragma unroll
        for (int r = 0; r < 4; r++) {
            int row = rbase + hi*4 + r;
            if (row < NN) P[(size_t)row*PD + ct*16 + lo] = __float2bfloat16(acc[r]);
        }
    }
}

// ---------------- CSR build ----------------
__global__ void k_zero(int* __restrict__ counts, int n) {
    int i = blockIdx.x * blockDim.x + threadIdx.x;
    if (i < n) counts[i] = 0;
}

__global__ void k_hist(const int* __restrict__ dst, int* __restrict__ counts, int e) {
    int i = blockIdx.x * blockDim.x + threadIdx.x;
    if (i < e) atomicAdd(&counts[dst[i]], 1);
}

__global__ __launch_bounds__(256) void k_bsum(const int* __restrict__ counts,
                                              int* __restrict__ bsum, int n) {
    __shared__ int ws[4];
    const int gid = blockIdx.x * 256 + threadIdx.x;
    const int lane = threadIdx.x & 63, wid = threadIdx.x >> 6;
    int v = (gid < n) ? counts[gid] : 0;
#pragma unroll
    for (int s = 1; s < 64; s <<= 1) v += __shfl_xor(v, s);
    if (lane == 0) ws[wid] = v;
    __syncthreads();
    if (threadIdx.x == 0) bsum[blockIdx.x] = ws[0] + ws[1] + ws[2] + ws[3];
}

__global__ __launch_bounds__(256) void k_bscan(const int* __restrict__ bsum,
                                               int* __restrict__ bpre,
                                               int* __restrict__ offsets, int nb) {
    __shared__ int ws[4];
    const int t = threadIdx.x, lane = t & 63, wid = t >> 6;
    int v = (t < nb) ? bsum[t] : 0;
    int sc = v;
#pragma unroll
    for (int s = 1; s < 64; s <<= 1) { int u = __shfl_up(sc, s); if (lane >= s) sc += u; }
    if (lane == 63) ws[wid] = sc;
    __syncthreads();
    int woff = 0;
    for (int k = 0; k < wid; k++) woff += ws[k];
    if (t < nb) bpre[t] = woff + sc - v;
    if (t == 0) offsets[NN] = NE;
}

__global__ __launch_bounds__(256) void k_apply(const int* __restrict__ counts,
                                               const int* __restrict__ bpre,
                                               int* __restrict__ offsets,
                                               int* __restrict__ cursor, int n) {
    __shared__ int ws[4];
    const int gid = blockIdx.x * 256 + threadIdx.x;
    const int t = threadIdx.x, lane = t & 63, wid = t >> 6;
    int v = (gid < n) ? counts[gid] : 0;
    int sc = v;
#pragma unroll
    for (int s = 1; s < 64; s <<= 1) { int u = __shfl_up(sc, s); if (lane >= s) sc += u; }
    if (lane == 63) ws[wid] = sc;
    __syncthreads();
    int woff = 0;
    for (int k = 0; k < wid; k++) woff += ws[k];
    const int ex = bpre[blockIdx.x] + woff + sc - v;
    if (gid < n) { offsets[gid] = ex; cursor[gid] = ex; }
}

__global__ void k_scatter(const int* __restrict__ dst,
                          int* __restrict__ cursor, int* __restrict__ eidx, int e) {
    int i = blockIdx.x * blockDim.x + threadIdx.x;
    if (i < e) {
        int p = atomicAdd(&cursor[dst[i]], 1);
        eidx[p] = i;
    }
}

// ---------------- K2: fused edge stage ----------------
// 512 threads / 8 waves / 128 edges per block. Wf staged once into transposed
// LDS (one ds_read_b128 per B-frag); P rows gathered async into LDS;
// f_out written via LDS transpose as contiguous wide wave stores.
__global__ __launch_bounds__(512) void k_edge(
    const float* __restrict__ efeats,
    const float* __restrict__ Wf,     // [32][64] f32
    const float* __restrict__ attn,   // [64] f32
    const float* __restrict__ bias,   // [64] f32
    const bf16* __restrict__ P,       // [NN][192] bf16
    const int* __restrict__ src, const int* __restrict__ dst,
    float* __restrict__ f_out,        // [NE][64] f32
    float* __restrict__ el)           // [NE][4]
{
    __shared__ __align__(16) __bf16 sP[2][128][64];  // 32KB, linear (gather dest)
    __shared__ __align__(16) __bf16 sWf[64][32];     // 4KB, [col][k]
    __shared__ int sIdx[2][128];
    const int t = threadIdx.x;
    const int lane = t & 63, wid = t >> 6;
    const int lo = lane & 15, hi = lane >> 4;
    const int e0 = blockIdx.x * 128;

    if (t < 128) sIdx[0][t] = src[e0 + t];
    else if (t < 256) sIdx[1][t - 128] = dst[e0 + t - 128];
    __syncthreads();

    // 2048 chunks of 16B (2 tables x 128 rows x 8 parts), 4 per thread.
#pragma unroll
    for (int q = 0; q < 4; q++) {
        int c = t + q * 512;
        int table = c >> 10, row = (c >> 3) & 127, part = c & 7;
        const bf16* g = P + (size_t)sIdx[table][row] * PD + table * 64 + part * 8;
        __bf16* ldsbase = &sP[0][0][0] + (size_t)(c & ~63) * 8;   // wave-uniform
        async_copy16(g, ldsbase);
    }

    // stage Wf transposed: thread reads one f32x4 (coalesced), writes 4 u16
    {
        int k  = t >> 4;
        int c4 = (t & 15) * 4;
        f32x4 w4 = *reinterpret_cast<const f32x4*>(&Wf[k * 64 + c4]);
#pragma unroll
        for (int i = 0; i < 4; i++) sWf[c4 + i][k] = (__bf16)w4[i];
    }

    bf16x8 afrag = load8_f32_to_bf16(&efeats[(size_t)(e0 + wid*16 + lo)*DEIN + hi*8]);

    __syncthreads();   // drains vmcnt (gathers) + lgkm (sWf) + barrier

    bf16x8 bfr[4];
#pragma unroll
    for (int ct = 0; ct < 4; ct++)
        bfr[ct] = *reinterpret_cast<const bf16x8*>(&sWf[ct*16 + lo][hi*8]);

    float v[4][4];     // [ct][r]
#pragma unroll
    for (int ct = 0; ct < 4; ct++) {
        f32x4 acc = {0.f, 0.f, 0.f, 0.f};
        acc = __builtin_amdgcn_mfma_f32_16x16x32_bf16(afrag, bfr[ct], acc, 0, 0, 0);
        const int c = ct*16 + lo;
        const float att = attn[c];
        const float bs  = bias[c];
#pragma unroll
        for (int r = 0; r < 4; r++) {
            const int lrow = wid*16 + hi*4 + r;
            float x = acc[r]
                    + __bfloat162float(sP[0][lrow][c])
                    + __bfloat162float(sP[1][lrow][c])
                    + bs;
            x = x > 0.f ? x : NEG_SLOPE * x;
            v[ct][r] = x;
            float s = x * att;
            s += __shfl_xor(s, 1);
            s += __shfl_xor(s, 2);
            s += __shfl_xor(s, 4);
            s += __shfl_xor(s, 8);
            if (lo == 0) el[(size_t)(e0 + lrow)*4 + ct] = s;
        }
    }

    __syncthreads();   // reuse sP as f32 transpose buffer (8 x 4KB)
    float* sOut = reinterpret_cast<float*>(&sP[0][0][0]) + wid * 1024;  // 16x64 f32
#pragma unroll
    for (int ct = 0; ct < 4; ct++)
#pragma unroll
        for (int r = 0; r < 4; r++)
            sOut[(hi*4 + r)*64 + ct*16 + lo] = v[ct][r];
#pragma unroll
    for (int q = 0; q < 4; q++) {
        const int lrow = (lane >> 4) + q*4;
        const int c4   = (lane & 15) * 4;
        f32x4 o = *reinterpret_cast<const f32x4*>(&sOut[lrow*64 + c4]);
        *reinterpret_cast<f32x4*>(&f_out[(size_t)(e0 + wid*16 + lrow)*64 + c4]) = o;
    }
}

// ---------------- K4: wave-per-node, 16-edge chunked online softmax + aggregation -------
__global__ __launch_bounds__(256) void k_aggregate(
    const int* __restrict__ offsets, const int* __restrict__ eidx,
    const int* __restrict__ src, const float* __restrict__ el,
    const bf16* __restrict__ P, float* __restrict__ h_out)
{
    const int lane = threadIdx.x & 63;
    const int wid  = threadIdx.x >> 6;
    const int n = blockIdx.x * 4 + wid;
    if (n >= NN) return;
    const int slot = lane & 15;
    const int grpBase = lane & 48;       // h*16
    const int h = lane >> 4;
    const int off0 = offsets[n], off1 = offsets[n + 1];

    float m = -3.0e38f, den = 0.f, acc = 0.f;
    for (int c0 = off0; c0 < off1; c0 += 16) {
        const int cnt = min(16, off1 - c0);
        float lv = -3.0e38f; int s = 0;
        if (slot < cnt) {
            const int e = eidx[c0 + slot];
            lv = el[(size_t)e*4 + h];
            s = src[e];
        }
        float cm = lv;
        cm = fmaxf(cm, __shfl_xor(cm, 1));
        cm = fmaxf(cm, __shfl_xor(cm, 2));
        cm = fmaxf(cm, __shfl_xor(cm, 4));
        cm = fmaxf(cm, __shfl_xor(cm, 8));
        const float nm = fmaxf(m, cm);
        const float scale = __expf(m - nm);
        const float w = (slot < cnt) ? __expf(lv - nm) : 0.f;
        float ws = w;
        ws += __shfl_xor(ws, 1);
        ws += __shfl_xor(ws, 2);
        ws += __shfl_xor(ws, 4);
        ws += __shfl_xor(ws, 8);
        den = den * scale + ws;
        acc *= scale;
        m = nm;

        float pv[16], wv[16];
#pragma unroll
        for (int q = 0; q < 16; q++) {
            const int sq = __shfl(s, grpBase + q);
            wv[q] = __shfl(w, grpBase + q);
            pv[q] = (q < cnt) ? __bfloat162float(P[(size_t)sq*PD + 128 + lane]) : 0.f;
        }
#pragma unroll
        for (int q = 0; q < 16; q++) acc += wv[q] * pv[q];
    }
    h_out[(size_t)n*64 + lane] = (off1 > off0) ? acc / den : 0.f;
}

extern "C" void kernel_launch(void* const* d_in, const int* in_sizes, int n_in,
                              void* d_out, int out_size, void* d_ws, size_t ws_size,
                              hipStream_t stream) {
    const float* nfeats = (const float*)d_in[0];
    const float* efeats = (const float*)d_in[1];
    const float* Wni    = (const float*)d_in[2];
    const float* Wnj    = (const float*)d_in[3];
    const float* Wfij   = (const float*)d_in[4];
    const float* Wnode  = (const float*)d_in[5];
    const float* attn   = (const float*)d_in[6];
    const float* bias   = (const float*)d_in[7];
    const int*   src    = (const int*)d_in[8];
    const int*   dst    = (const int*)d_in[9];

    float* h_out = (float*)d_out;                           // [NN*64]
    float* f_out = (float*)d_out + (size_t)NN * 64;         // [NE*64]

    char* ws = (char*)d_ws;
    size_t off = 0;
    auto carve = [&](size_t bytes) -> void* {
        void* p = ws + off;
        off = (off + bytes + 255) & ~(size_t)255;
        return p;
    };
    const int NB = (NN + 255) / 256;    // 196 scan blocks
    bf16*  P       = (bf16*) carve((size_t)NN * PD * sizeof(bf16));
    float* el      = (float*)carve((size_t)NE * 4 * sizeof(float));
    int*   counts  = (int*)  carve((size_t)NN * sizeof(int));
    int*   cursor  = (int*)  carve((size_t)NN * sizeof(int));
    int*   offsets = (int*)  carve((size_t)(NN + 1) * sizeof(int));
    int*   eidx    = (int*)  carve((size_t)NE * sizeof(int));
    int*   bsum    = (int*)  carve((size_t)NB * sizeof(int));
    int*   bpre    = (int*)  carve((size_t)NB * sizeof(int));
    (void)ws_size; (void)in_sizes; (void)n_in; (void)out_size;

    hipLaunchKernelGGL(k_zero, dim3(NB), dim3(256), 0, stream, counts, NN);
    hipLaunchKernelGGL(k_node_gemm, dim3((NN + 127) / 128), dim3(512), 0, stream,
                       nfeats, Wni, Wnj, Wnode, P);
    hipLaunchKernelGGL(k_hist, dim3((NE + 255) / 256), dim3(256), 0, stream,
                       dst, counts, NE);
    hipLaunchKernelGGL(k_bsum, dim3(NB), dim3(256), 0, stream, counts, bsum, NN);
    hipLaunchKernelGGL(k_bscan, dim3(1), dim3(256), 0, stream, bsum, bpre, offsets, NB);
    hipLaunchKernelGGL(k_apply, dim3(NB), dim3(256), 0, stream,
                       counts, bpre, offsets, cursor, NN);
    hipLaunchKernelGGL(k_scatter, dim3((NE + 255) / 256), dim3(256), 0, stream,
                       dst, cursor, eidx, NE);
    hipLaunchKernelGGL(k_edge, dim3(NE / 128), dim3(512), 0, stream,
                       efeats, Wfij, attn, bias, P, src, dst, f_out, el);
    hipLaunchKernelGGL(k_aggregate, dim3((NN + 3) / 4), dim3(256), 0, stream,
                       offsets, eidx, src, el, P, h_out);
}